// Round 6
// baseline (3041.151 us; speedup 1.0000x reference)
//
#include <hip/hip_runtime.h>
#include <math.h>

// ---------------- problem constants ----------------
// B=4, H=1024, W=1536; Hf=64, Wf=96; C=64; grid 256x256; D=16 depth bins.
// conv chain: (3,1024,1536)->(32,512,768)->(64,256,384)->(128,128,192)->(128,64,96)
//
// NUMERICS LEDGER:
//  R1 naive conv1/conv2: PASS 0.015625. Every restructured conv1/conv2 BODY
//  fails at exactly 0.203125 (knife-edge p* flips between fast-math
//  realizations). conv3/4/fw1 tiled (__builtin_fmaf) PASS — fmaf is
//  non-reassociable, so any change preserving the per-output ic->ky->kx
//  chain order is BIT-IDENTICAL (staging-batch changes are free).
//  => conv1/conv2 BODIES LOCKED (R1 source); launch-order permutations ok.
//
//  SCHEDULE LEDGER:
//   R0 (no interleave): conv2 = 1690us, VALUBusy 38% (201MB conv1 out +
//      75MB images overflow 256MB L3 before conv2 starts -> HBM misses).
//   R3 (4-chunk interleave): conv2 = 1465us; FETCH/chunk = compulsory 25MB
//      (within-dispatch L2 reuse perfect; win was HBM->L3). BEST: 2829us.
//   R4 (8-chunk): REGRESSED 2974 — cross-dispatch L2 reuse impossible
//      (kernel-boundary release/acquire invalidates per-XCD L2); finer
//      chunks only add overhead. conv2 model: stride-2 lanes -> 8 lines
//      per wave-load -> ~8cy/load request-rate wall; body locked => floor.
//   R5 (tile split conv3/4/fw1 for occupancy): REGRESSED +70us — per-ic
//      LDS staging + syncthreads overhead doubled; occupancy-by-more-blocks
//      is a dead lever on these shapes.
//   THIS ROUND: R3 schedule verbatim + 4-ic-per-sync staging in the tiled
//      convs (barriers /4, staging loads batched; fmaf chains untouched).

// ---------- R1-verbatim naive conv body; chunked launch permutation ----------
// conv1: SPG=192, grid/chunk = 8*192*32 = 49152 (chunk k = rows [128k,128k+128))
// conv2: SPG=48,  grid/chunk = 8*48*64  = 24576 (chunk k = rows [64k,64k+64))
// x = blk&7 -> XCD (round-robin): b = x>>1, g = x&1 (row-half within chunk).
template<int STRIDE, int OCL2, int SPG>
__global__ __launch_bounds__(256) void conv3x3_chunk(
    const float* __restrict__ in, const float* __restrict__ wgt,
    const float* __restrict__ scl, const float* __restrict__ sft,
    float* __restrict__ out,
    int IC, int IH, int IW, int OC, int OH, int OW, int k) {
  __shared__ float wl[1152];  // up to IC=128 * 9
  // --- launch-order permutation (bijection on 256-output chunks) ---
  int chw = (OH * OW) >> 8;            // slabs per (b,oc) plane
  int x = blockIdx.x & 7;              // -> XCD (round-robin dispatch heuristic)
  int y = blockIdx.x >> 3;
  int b_sel = x >> 1;                  // batch pinned to XCD pair
  int g = x & 1;                       // row-half group within chunk
  int oc_r = y & ((1 << OCL2) - 1);    // oc fastest: same-slab blocks adjacent in time
  int s_loc = y >> OCL2;               // [0, SPG)
  int s = k * (2 * SPG) + g * SPG + s_loc;   // global slab within (b,oc) plane
  int chunk = (b_sel * OC + oc_r) * chw + s;
  int idx = chunk * 256 + threadIdx.x;
  // --- body identical to R1 naive kernel from here on ---
  int ox = idx % OW;
  int tmp = idx / OW;
  int oy = tmp % OH;
  tmp /= OH;
  int oc = tmp % OC;
  int b = tmp / OC;
  int wn = IC * 9;
  for (int i = threadIdx.x; i < wn; i += 256) wl[i] = wgt[oc * wn + i];
  __syncthreads();

  const float* ip0 = in + (b * IC) * IH * IW;
  int iy0 = oy * STRIDE - 1;
  int ix0 = ox * STRIDE - 1;
  int plane = IH * IW;
  float acc = 0.f;
  if (iy0 >= 0 && iy0 + 2 < IH && ix0 >= 0 && ix0 + 2 < IW) {
    const float* ip = ip0 + iy0 * IW + ix0;
    const float* wp = wl;
    for (int ic = 0; ic < IC; ++ic) {
#pragma unroll
      for (int ky = 0; ky < 3; ++ky) {
        const float* r = ip + ky * IW;
        acc += r[0] * wp[ky * 3 + 0];
        acc += r[1] * wp[ky * 3 + 1];
        acc += r[2] * wp[ky * 3 + 2];
      }
      ip += plane;
      wp += 9;
    }
  } else {
    for (int ic = 0; ic < IC; ++ic) {
      const float* ip = ip0 + ic * plane;
      const float* wp = wl + ic * 9;
#pragma unroll
      for (int ky = 0; ky < 3; ++ky) {
        int iy = iy0 + ky;
        if (iy < 0 || iy >= IH) continue;
#pragma unroll
        for (int kx = 0; kx < 3; ++kx) {
          int ix = ix0 + kx;
          if (ix < 0 || ix >= IW) continue;
          acc += ip[iy * IW + ix] * wp[ky * 3 + kx];
        }
      }
    }
  }
  float r = acc * scl[oc] + sft[oc];
  out[idx] = r > 0.f ? r : 0.f;
}

// ---------- tiled conv (conv3, conv4, fw1) — 4-ic-per-sync staging ----------
// Per-output fmaf chain is ic->ky->kx ascending, identical to the verified
// R5-tiled kernel (fmaf non-reassociable => bit-identical outputs).
template<int STRIDE, int IC, int OCB, int OCT, int NOC4, int TY, int TX>
__global__ __launch_bounds__(256) void conv3x3_t(
    const float* __restrict__ in, const float* __restrict__ wgt,
    const float* __restrict__ scl, const float* __restrict__ sft,
    float* __restrict__ out, int IH, int IW, int OH, int OW) {
  constexpr int OCG = NOC4 * 4;
  constexpr int NOCG = OCB / OCG;
  constexpr int NPIX_T = 256 / NOCG;
  constexpr int PIX = (TY * TX) / NPIX_T;
  constexpr int PH = (TY - 1) * STRIDE + 3;
  constexpr int PW = (TX - 1) * STRIDE + 3;
  constexpr int ICS = 4;               // ics staged per sync round
  __shared__ float patch[ICS][PH * PW];
  __shared__ float wl[ICS][9 * OCB];

  int NTY = OH / TY, NTX = OW / TX;
  int ntiles = 4 * NTY * NTX;
  int ocs = blockIdx.x / ntiles;
  int r = blockIdx.x % ntiles;
  int b = r / (NTY * NTX);
  int t = r % (NTY * NTX);
  int tyi = t / NTX, txi = t % NTX;
  int oc_base = ocs * OCB;

  int tid = threadIdx.x;
  int pid = tid % NPIX_T;
  int ocg = tid / NPIX_T;

  int off[PIX], pyv[PIX], pxv[PIX];
#pragma unroll
  for (int i = 0; i < PIX; ++i) {
    int p = i * NPIX_T + pid;
    pyv[i] = p / TX;
    pxv[i] = p % TX;
    off[i] = (pyv[i] * STRIDE) * PW + pxv[i] * STRIDE;
  }

  float4 acc[PIX][NOC4];
#pragma unroll
  for (int i = 0; i < PIX; ++i)
#pragma unroll
    for (int j = 0; j < NOC4; ++j) acc[i][j] = make_float4(0.f, 0.f, 0.f, 0.f);

  const size_t plane_in = (size_t)IH * IW;
  const float* ibase = in + (size_t)b * IC * plane_in;
  int iy0 = tyi * TY * STRIDE - 1;
  int ix0 = txi * TX * STRIDE - 1;

#pragma unroll 1
  for (int ic0 = 0; ic0 < IC; ic0 += ICS) {
    // stage ICS planes of patch + weights, one barrier pair per round
#pragma unroll
    for (int u = 0; u < ICS; ++u) {
      const float* ip = ibase + (size_t)(ic0 + u) * plane_in;
      for (int i = tid; i < PH * PW; i += 256) {
        int py = i / PW, px = i % PW;
        int iy = iy0 + py, ix = ix0 + px;
        float v = 0.f;
        if (iy >= 0 && iy < IH && ix >= 0 && ix < IW) v = ip[(size_t)iy * IW + ix];
        patch[u][i] = v;
      }
      for (int i = tid; i < 9 * OCB; i += 256) {
        int oc = i / 9, kk = i % 9;
        wl[u][kk * OCB + oc] = wgt[((size_t)(oc_base + oc) * IC + ic0 + u) * 9 + kk];
      }
    }
    __syncthreads();

#pragma unroll
    for (int u = 0; u < ICS; ++u) {
      const float4* wl4 = (const float4*)wl[u];
#pragma unroll
      for (int ky = 0; ky < 3; ++ky) {
#pragma unroll
        for (int kx = 0; kx < 3; ++kx) {
          float pv[PIX];
#pragma unroll
          for (int i = 0; i < PIX; ++i) pv[i] = patch[u][off[i] + ky * PW + kx];
          const float4* wr = wl4 + (ky * 3 + kx) * (OCB / 4) + ocg * NOC4;
#pragma unroll
          for (int j = 0; j < NOC4; ++j) {
            float4 w = wr[j];
#pragma unroll
            for (int i = 0; i < PIX; ++i) {
              acc[i][j].x = __builtin_fmaf(pv[i], w.x, acc[i][j].x);
              acc[i][j].y = __builtin_fmaf(pv[i], w.y, acc[i][j].y);
              acc[i][j].z = __builtin_fmaf(pv[i], w.z, acc[i][j].z);
              acc[i][j].w = __builtin_fmaf(pv[i], w.w, acc[i][j].w);
            }
          }
        }
      }
    }
    __syncthreads();
  }

  int plane = OH * OW;
#pragma unroll
  for (int i = 0; i < PIX; ++i) {
    int oy = tyi * TY + pyv[i];
    int ox = txi * TX + pxv[i];
#pragma unroll
    for (int j = 0; j < NOC4; ++j) {
      int oc0 = oc_base + ocg * OCG + j * 4;
      float4 v = acc[i][j];
      float4 sc = ((const float4*)scl)[oc0 >> 2];
      float4 sh = ((const float4*)sft)[oc0 >> 2];
      float rx = __builtin_fmaf(v.x, sc.x, sh.x);
      float ry = __builtin_fmaf(v.y, sc.y, sh.y);
      float rz = __builtin_fmaf(v.z, sc.z, sh.z);
      float rw = __builtin_fmaf(v.w, sc.w, sh.w);
      rx = rx > 0.f ? rx : 0.f;
      ry = ry > 0.f ? ry : 0.f;
      rz = rz > 0.f ? rz : 0.f;
      rw = rw > 0.f ? rw : 0.f;
      size_t base = ((size_t)b * OCT + oc0) * plane + oy * OW + ox;
      out[base] = rx;
      out[base + plane] = ry;
      out[base + 2 * (size_t)plane] = rz;
      out[base + 3 * (size_t)plane] = rw;
    }
  }
}

// 1x1 conv 128->64 + bias, output (B, Hf, Wf, C). (R1-verbatim)
__global__ __launch_bounds__(256) void feat_head(
    const float* __restrict__ fh, const float* __restrict__ fw2,
    const float* __restrict__ fb, float* __restrict__ feats) {
  __shared__ float wl[128 * 64];
  for (int i = threadIdx.x; i < 8192; i += 256) {
    int c = i & 63, ic = i >> 6;
    wl[i] = fw2[c * 128 + ic];
  }
  __syncthreads();
  int t = blockIdx.x * 256 + threadIdx.x;
  int c = t & 63;
  int p = t >> 6;
  int b = p / 6144;
  int rem = p % 6144;
  const float* fp = fh + (b * 128) * 6144 + rem;
  float acc = fb[c];
#pragma unroll 4
  for (int ic = 0; ic < 128; ++ic) acc += fp[ic * 6144] * wl[(ic << 6) + c];
  feats[t] = acc;
}

// depth/opacity heads + backprojection + voxelization. (R1-verbatim)
__global__ __launch_bounds__(256) void depth_head(
    const float* __restrict__ x4, const float* __restrict__ dw,
    const float* __restrict__ dbias, const float* __restrict__ oww,
    const float* __restrict__ obias, const float* __restrict__ camK,
    const float* __restrict__ Tlc,
    int* __restrict__ xio, int* __restrict__ yio, float* __restrict__ bwo) {
  __shared__ float dwl[16 * 128];
  __shared__ float owl[128];
  for (int i = threadIdx.x; i < 2048; i += 256) dwl[i] = dw[i];
  if (threadIdx.x < 128) owl[threadIdx.x] = oww[threadIdx.x];
  __syncthreads();
  int p = blockIdx.x * 256 + threadIdx.x;
  int b = p / 6144;
  int rem = p % 6144;
  int y = rem / 96;
  int x = rem % 96;

  float lg[16];
#pragma unroll
  for (int j = 0; j < 16; ++j) lg[j] = dbias[j];
  float oa = obias[0];
  const float* fp = x4 + (b * 128) * 6144 + rem;
  for (int ic = 0; ic < 128; ++ic) {
    float f = fp[ic * 6144];
#pragma unroll
    for (int j = 0; j < 16; ++j) lg[j] += f * dwl[j * 128 + ic];
    oa += f * owl[ic];
  }
  float m = lg[0];
#pragma unroll
  for (int j = 1; j < 16; ++j) m = fmaxf(m, lg[j]);
  float se = 0.f, sz = 0.f;
#pragma unroll
  for (int j = 0; j < 16; ++j) {
    float e = expf(lg[j] - m);
    se += e;
    sz += e * (1.0f + (float)j * (59.0f / 15.0f));
  }
  float z = sz / se;
  float op = 1.f / (1.f + expf(-oa));

  const float* K = camK + b * 9;
  float fx = fmaxf(K[0], 1e-6f), fy = fmaxf(K[4], 1e-6f);
  float cx = K[2], cy = K[5];
  float xs = ((float)x + 0.5f) * 16.0f;
  float ys = ((float)y + 0.5f) * 16.0f;
  float xc = (xs - cx) * z / fx;
  float yc = (ys - cy) * z / fy;
  const float* T = Tlc + b * 16;
  float xw = T[0] * xc + T[1] * yc + T[2] * z + T[3];
  float yw = T[4] * xc + T[5] * yc + T[6] * z + T[7];
  float zw = T[8] * xc + T[9] * yc + T[10] * z + T[11];
  float xif = floorf((xw - (-51.2f)) / 0.4f);
  float yif = floorf((yw - (-51.2f)) / 0.4f);
  int xi = (int)xif, yi = (int)yif;
  bool inb = xi >= 0 && xi < 256 && yi >= 0 && yi < 256 && zw >= -5.0f && zw < 3.0f;
  float bw = (op >= 0.05f && inb) ? op : 0.f;
  xio[p] = xi;
  yio[p] = yi;
  bwo[p] = bw;
}

__global__ __launch_bounds__(256) void zerof4(float4* __restrict__ p) {
  int i = blockIdx.x * 256 + threadIdx.x;
  p[i] = make_float4(0.f, 0.f, 0.f, 0.f);
}

// 9-tap Gaussian scatter. (R1-verbatim)
__global__ __launch_bounds__(256) void splat(
    const float* __restrict__ feats, const int* __restrict__ xi,
    const int* __restrict__ yi, const float* __restrict__ bw,
    float* __restrict__ canvas, float* __restrict__ wacc) {
  int t = blockIdx.x * 256 + threadIdx.x;
  int c = t & 63;
  int p = t >> 6;
  float w0 = bw[p];
  if (w0 == 0.f) return;
  int X = xi[p], Y = yi[p];
  int b = p / 6144;
  float fv = feats[t];
  float* cb = canvas + ((size_t)b << 22);
  float* wb = wacc + (b << 16);
  const float kwt[3] = {1.0f, 0.45783335f, 0.20961137f};
#pragma unroll
  for (int dy = -1; dy <= 1; ++dy) {
    int ty = Y + dy;
    if (ty < 0 || ty > 255) continue;
#pragma unroll
    for (int dx = -1; dx <= 1; ++dx) {
      int tx = X + dx;
      if (tx < 0 || tx > 255) continue;
      float kw = kwt[dx * dx + dy * dy];
      atomicAdd(&cb[(((ty << 8) + tx) << 6) + c], fv * w0 * kw);
      if (c == 0) atomicAdd(&wb[(ty << 8) + tx], w0 * kw);
    }
  }
}

// normalize + NHWC->NCHW transpose. (R1-verbatim)
__global__ __launch_bounds__(256) void normalize_out(
    const float* __restrict__ canvas, const float* __restrict__ wacc,
    float* __restrict__ out) {
  __shared__ float tile[64][65];
  int blk = blockIdx.x;
  int b = blk >> 10;
  int s0 = (blk & 1023) << 6;
  int tid = threadIdx.x;
  const float* cb = canvas + ((size_t)b << 22);
  const float* wb = wacc + (b << 16);
#pragma unroll
  for (int it = 0; it < 16; ++it) {
    int l = it * 256 + tid;
    int pix = l >> 6, ch = l & 63;
    float w = wb[s0 + pix];
    float n = w > 0.f ? 1.f / fmaxf(w, 1e-6f) : 0.f;
    tile[pix][ch] = cb[(size_t)(s0 + pix) * 64 + ch] * n;
  }
  __syncthreads();
  float* ob = out + ((size_t)b << 22);
#pragma unroll
  for (int it = 0; it < 16; ++it) {
    int l = it * 256 + tid;
    int ch = l >> 6, pix = l & 63;
    ob[(size_t)ch * 65536 + s0 + pix] = tile[pix][ch];
  }
}

extern "C" void kernel_launch(void* const* d_in, const int* in_sizes, int n_in,
                              void* d_out, int out_size, void* d_ws, size_t ws_size,
                              hipStream_t stream) {
  const float* images = (const float*)d_in[0];
  const float* camK   = (const float*)d_in[1];
  const float* Tlc    = (const float*)d_in[2];
  const float* w1 = (const float*)d_in[3];
  const float* s1 = (const float*)d_in[4];
  const float* b1 = (const float*)d_in[5];
  const float* w2 = (const float*)d_in[6];
  const float* s2 = (const float*)d_in[7];
  const float* b2 = (const float*)d_in[8];
  const float* w3 = (const float*)d_in[9];
  const float* s3 = (const float*)d_in[10];
  const float* b3 = (const float*)d_in[11];
  const float* w4 = (const float*)d_in[12];
  const float* s4 = (const float*)d_in[13];
  const float* b4 = (const float*)d_in[14];
  const float* fw1 = (const float*)d_in[15];
  const float* fs1 = (const float*)d_in[16];
  const float* fb1 = (const float*)d_in[17];
  const float* fw2 = (const float*)d_in[18];
  const float* fbias2 = (const float*)d_in[19];
  const float* dw = (const float*)d_in[20];
  const float* dbias = (const float*)d_in[21];
  const float* ow = (const float*)d_in[22];
  const float* obias = (const float*)d_in[23];
  float* out = (float*)d_out;

  // workspace layout (floats), aliased (same as R1/R5/R6):
  //   A [50,331,648]: conv1 out -> conv3 out (12.58M) -> canvas(16.78M)+wacc(0.26M)
  //   B [25,165,824]: conv2 out -> c4(3.15M) | fh(3.15M) | feats(1.57M) | xi/yi/bw
  float* ws = (float*)d_ws;
  float* A = ws;
  float* Bb = ws + 50331648;
  float* c4   = Bb;
  float* fhb  = Bb + 3145728;
  float* ftb  = Bb + 6291456;
  int*   xib  = (int*)(Bb + 7864320);
  int*   yib  = xib + 24576;
  float* bwb  = (float*)(yib + 24576);
  float* canvas = A;
  float* waccb  = A + 16777216;

  // Temporal chunk interleave (4 pairs — R3 best): conv1 rows [128k,128k+128)
  // then conv2 rows [64k,64k+64) (reads conv1 rows [128k-1,128k+127] ->
  // chunks <=k only; stream order satisfies the dependency).
  for (int k = 0; k < 4; ++k) {
    conv3x3_chunk<2, 5, 192><<<49152, 256, 0, stream>>>(
        images, w1, s1, b1, A, 3, 1024, 1536, 32, 512, 768, k);
    conv3x3_chunk<2, 6, 48><<<24576, 256, 0, stream>>>(
        A, w2, s2, b2, Bb, 32, 512, 768, 64, 256, 384, k);
  }
  // conv3, conv4, fw1: R3 grid shapes (768 blocks — measured best), with
  // 4-ic-per-sync staging (barriers /4, batched staging loads).
  conv3x3_t<2, 64, 64, 128, 8, 8, 32><<<768, 256, 0, stream>>>(
      Bb, w3, s3, b3, A, 256, 384, 128, 192);
  conv3x3_t<2, 128, 32, 128, 4, 8, 16><<<768, 256, 0, stream>>>(
      A, w4, s4, b4, c4, 128, 192, 64, 96);
  conv3x3_t<1, 128, 32, 128, 4, 8, 16><<<768, 256, 0, stream>>>(
      c4, fw1, fs1, fb1, fhb, 64, 96, 64, 96);
  feat_head<<<6144, 256, 0, stream>>>(fhb, fw2, fbias2, ftb);
  depth_head<<<96, 256, 0, stream>>>(c4, dw, dbias, ow, obias, camK, Tlc, xib, yib, bwb);
  zerof4<<<16640, 256, 0, stream>>>((float4*)canvas);
  splat<<<6144, 256, 0, stream>>>(ftb, xib, yib, bwb, canvas, waccb);
  normalize_out<<<4096, 256, 0, stream>>>(canvas, waccb, out);
}

// Round 7
// 2828.948 us; speedup vs baseline: 1.0750x; 1.0750x over previous
//
#include <hip/hip_runtime.h>
#include <math.h>

// ---------------- problem constants ----------------
// B=4, H=1024, W=1536; Hf=64, Wf=96; C=64; grid 256x256; D=16 depth bins.
// conv chain: (3,1024,1536)->(32,512,768)->(64,256,384)->(128,128,192)->(128,64,96)
//
// NUMERICS LEDGER:
//  R1 naive conv1/conv2: PASS 0.015625. Every restructured conv1/conv2 BODY
//  fails at exactly 0.203125 (knife-edge p* flips between fast-math
//  realizations). conv3/4/fw1 tiled (__builtin_fmaf) PASS — fmaf is
//  non-reassociable; any change preserving the per-output ic->ky->kx chain
//  (e.g. LDS layout padding) is BIT-IDENTICAL.
//  => conv1/conv2 BODIES LOCKED (R1 source); launch-order permutations ok.
//
//  SCHEDULE LEDGER (R3 = local optimum, 2829us):
//   R0 no interleave: conv2 1690us (L3 overflow -> HBM misses).
//   R3 4-chunk interleave: conv2 4x366us; FETCH/chunk = compulsory 25MB;
//      win was HBM->L3. BEST 2829us.
//   R4 8-chunk: REGRESSED (cross-dispatch L2 reuse impossible: kernel-
//      boundary release/acquire invalidates per-XCD L2). conv2 model:
//      stride-2 lanes -> 8 lines/wave-load -> ~8cy/load request wall;
//      body locked => conv2 floor ~1465us.
//   R5 tile split conv3/4/fw1: REGRESSED +70us (staging overhead > occ gain).
//   R6 4-ic staging: REGRESSED +210us (LDS 7->27KB, occ 32->18%).
//   => R3 config for everything; THIS ROUND adds only a layout-pure fix:
//      wl row pad OCB->OCB+4 kills the 9-way bank conflict in weight
//      staging (SQ_LDS_BANK_CONFLICT 1.18e7 on conv3; writes kk*OCB+oc
//      were stride-64-floats = same bank for kk=0..8).

// ---------- R1-verbatim naive conv body; chunked launch permutation ----------
// conv1: SPG=192, grid/chunk = 8*192*32 = 49152 (chunk k = rows [128k,128k+128))
// conv2: SPG=48,  grid/chunk = 8*48*64  = 24576 (chunk k = rows [64k,64k+64))
// x = blk&7 -> XCD (round-robin): b = x>>1, g = x&1 (row-half within chunk).
template<int STRIDE, int OCL2, int SPG>
__global__ __launch_bounds__(256) void conv3x3_chunk(
    const float* __restrict__ in, const float* __restrict__ wgt,
    const float* __restrict__ scl, const float* __restrict__ sft,
    float* __restrict__ out,
    int IC, int IH, int IW, int OC, int OH, int OW, int k) {
  __shared__ float wl[1152];  // up to IC=128 * 9
  // --- launch-order permutation (bijection on 256-output chunks) ---
  int chw = (OH * OW) >> 8;            // slabs per (b,oc) plane
  int x = blockIdx.x & 7;              // -> XCD (round-robin dispatch heuristic)
  int y = blockIdx.x >> 3;
  int b_sel = x >> 1;                  // batch pinned to XCD pair
  int g = x & 1;                       // row-half group within chunk
  int oc_r = y & ((1 << OCL2) - 1);    // oc fastest: same-slab blocks adjacent in time
  int s_loc = y >> OCL2;               // [0, SPG)
  int s = k * (2 * SPG) + g * SPG + s_loc;   // global slab within (b,oc) plane
  int chunk = (b_sel * OC + oc_r) * chw + s;
  int idx = chunk * 256 + threadIdx.x;
  // --- body identical to R1 naive kernel from here on ---
  int ox = idx % OW;
  int tmp = idx / OW;
  int oy = tmp % OH;
  tmp /= OH;
  int oc = tmp % OC;
  int b = tmp / OC;
  int wn = IC * 9;
  for (int i = threadIdx.x; i < wn; i += 256) wl[i] = wgt[oc * wn + i];
  __syncthreads();

  const float* ip0 = in + (b * IC) * IH * IW;
  int iy0 = oy * STRIDE - 1;
  int ix0 = ox * STRIDE - 1;
  int plane = IH * IW;
  float acc = 0.f;
  if (iy0 >= 0 && iy0 + 2 < IH && ix0 >= 0 && ix0 + 2 < IW) {
    const float* ip = ip0 + iy0 * IW + ix0;
    const float* wp = wl;
    for (int ic = 0; ic < IC; ++ic) {
#pragma unroll
      for (int ky = 0; ky < 3; ++ky) {
        const float* r = ip + ky * IW;
        acc += r[0] * wp[ky * 3 + 0];
        acc += r[1] * wp[ky * 3 + 1];
        acc += r[2] * wp[ky * 3 + 2];
      }
      ip += plane;
      wp += 9;
    }
  } else {
    for (int ic = 0; ic < IC; ++ic) {
      const float* ip = ip0 + ic * plane;
      const float* wp = wl + ic * 9;
#pragma unroll
      for (int ky = 0; ky < 3; ++ky) {
        int iy = iy0 + ky;
        if (iy < 0 || iy >= IH) continue;
#pragma unroll
        for (int kx = 0; kx < 3; ++kx) {
          int ix = ix0 + kx;
          if (ix < 0 || ix >= IW) continue;
          acc += ip[iy * IW + ix] * wp[ky * 3 + kx];
        }
      }
    }
  }
  float r = acc * scl[oc] + sft[oc];
  out[idx] = r > 0.f ? r : 0.f;
}

// ---------- tiled conv (conv3, conv4, fw1) — R3 config + padded wl rows ----------
// Per-output fmaf chain ic->ky->kx unchanged (bit-identical). OCP = OCB+4
// pads each kk-row of wl so staging writes (stride OCP floats) spread
// across banks instead of 9-way colliding at stride OCB=64/32.
template<int STRIDE, int IC, int OCB, int OCT, int NOC4, int TY, int TX>
__global__ __launch_bounds__(256) void conv3x3_t(
    const float* __restrict__ in, const float* __restrict__ wgt,
    const float* __restrict__ scl, const float* __restrict__ sft,
    float* __restrict__ out, int IH, int IW, int OH, int OW) {
  constexpr int OCG = NOC4 * 4;
  constexpr int NOCG = OCB / OCG;
  constexpr int NPIX_T = 256 / NOCG;
  constexpr int PIX = (TY * TX) / NPIX_T;
  constexpr int PH = (TY - 1) * STRIDE + 3;
  constexpr int PW = (TX - 1) * STRIDE + 3;
  constexpr int OCP = OCB + 4;         // padded row: stride 68/36 floats
  __shared__ float patch[PH * PW];
  __shared__ float wl[9 * OCP];

  int NTY = OH / TY, NTX = OW / TX;
  int ntiles = 4 * NTY * NTX;
  int ocs = blockIdx.x / ntiles;
  int r = blockIdx.x % ntiles;
  int b = r / (NTY * NTX);
  int t = r % (NTY * NTX);
  int tyi = t / NTX, txi = t % NTX;
  int oc_base = ocs * OCB;

  int tid = threadIdx.x;
  int pid = tid % NPIX_T;
  int ocg = tid / NPIX_T;

  int off[PIX], pyv[PIX], pxv[PIX];
#pragma unroll
  for (int i = 0; i < PIX; ++i) {
    int p = i * NPIX_T + pid;
    pyv[i] = p / TX;
    pxv[i] = p % TX;
    off[i] = (pyv[i] * STRIDE) * PW + pxv[i] * STRIDE;
  }

  float4 acc[PIX][NOC4];
#pragma unroll
  for (int i = 0; i < PIX; ++i)
#pragma unroll
    for (int j = 0; j < NOC4; ++j) acc[i][j] = make_float4(0.f, 0.f, 0.f, 0.f);

  const size_t plane_in = (size_t)IH * IW;
  const float* ibase = in + (size_t)b * IC * plane_in;
  int iy0 = tyi * TY * STRIDE - 1;
  int ix0 = txi * TX * STRIDE - 1;

#pragma unroll 1
  for (int ic = 0; ic < IC; ++ic) {
    const float* ip = ibase + (size_t)ic * plane_in;
    for (int i = tid; i < PH * PW; i += 256) {
      int py = i / PW, px = i % PW;
      int iy = iy0 + py, ix = ix0 + px;
      float v = 0.f;
      if (iy >= 0 && iy < IH && ix >= 0 && ix < IW) v = ip[(size_t)iy * IW + ix];
      patch[i] = v;
    }
    for (int i = tid; i < 9 * OCB; i += 256) {
      int oc = i / 9, kk = i % 9;
      wl[kk * OCP + oc] = wgt[((size_t)(oc_base + oc) * IC + ic) * 9 + kk];
    }
    __syncthreads();

    const float4* wl4 = (const float4*)wl;
#pragma unroll
    for (int ky = 0; ky < 3; ++ky) {
#pragma unroll
      for (int kx = 0; kx < 3; ++kx) {
        float pv[PIX];
#pragma unroll
        for (int i = 0; i < PIX; ++i) pv[i] = patch[off[i] + ky * PW + kx];
        const float4* wr = wl4 + (ky * 3 + kx) * (OCP / 4) + ocg * NOC4;
#pragma unroll
        for (int j = 0; j < NOC4; ++j) {
          float4 w = wr[j];
#pragma unroll
          for (int i = 0; i < PIX; ++i) {
            acc[i][j].x = __builtin_fmaf(pv[i], w.x, acc[i][j].x);
            acc[i][j].y = __builtin_fmaf(pv[i], w.y, acc[i][j].y);
            acc[i][j].z = __builtin_fmaf(pv[i], w.z, acc[i][j].z);
            acc[i][j].w = __builtin_fmaf(pv[i], w.w, acc[i][j].w);
          }
        }
      }
    }
    __syncthreads();
  }

  int plane = OH * OW;
#pragma unroll
  for (int i = 0; i < PIX; ++i) {
    int oy = tyi * TY + pyv[i];
    int ox = txi * TX + pxv[i];
#pragma unroll
    for (int j = 0; j < NOC4; ++j) {
      int oc0 = oc_base + ocg * OCG + j * 4;
      float4 v = acc[i][j];
      float4 sc = ((const float4*)scl)[oc0 >> 2];
      float4 sh = ((const float4*)sft)[oc0 >> 2];
      float rx = __builtin_fmaf(v.x, sc.x, sh.x);
      float ry = __builtin_fmaf(v.y, sc.y, sh.y);
      float rz = __builtin_fmaf(v.z, sc.z, sh.z);
      float rw = __builtin_fmaf(v.w, sc.w, sh.w);
      rx = rx > 0.f ? rx : 0.f;
      ry = ry > 0.f ? ry : 0.f;
      rz = rz > 0.f ? rz : 0.f;
      rw = rw > 0.f ? rw : 0.f;
      size_t base = ((size_t)b * OCT + oc0) * plane + oy * OW + ox;
      out[base] = rx;
      out[base + plane] = ry;
      out[base + 2 * (size_t)plane] = rz;
      out[base + 3 * (size_t)plane] = rw;
    }
  }
}

// 1x1 conv 128->64 + bias, output (B, Hf, Wf, C). (R1-verbatim)
__global__ __launch_bounds__(256) void feat_head(
    const float* __restrict__ fh, const float* __restrict__ fw2,
    const float* __restrict__ fb, float* __restrict__ feats) {
  __shared__ float wl[128 * 64];
  for (int i = threadIdx.x; i < 8192; i += 256) {
    int c = i & 63, ic = i >> 6;
    wl[i] = fw2[c * 128 + ic];
  }
  __syncthreads();
  int t = blockIdx.x * 256 + threadIdx.x;
  int c = t & 63;
  int p = t >> 6;
  int b = p / 6144;
  int rem = p % 6144;
  const float* fp = fh + (b * 128) * 6144 + rem;
  float acc = fb[c];
#pragma unroll 4
  for (int ic = 0; ic < 128; ++ic) acc += fp[ic * 6144] * wl[(ic << 6) + c];
  feats[t] = acc;
}

// depth/opacity heads + backprojection + voxelization. (R1-verbatim)
__global__ __launch_bounds__(256) void depth_head(
    const float* __restrict__ x4, const float* __restrict__ dw,
    const float* __restrict__ dbias, const float* __restrict__ oww,
    const float* __restrict__ obias, const float* __restrict__ camK,
    const float* __restrict__ Tlc,
    int* __restrict__ xio, int* __restrict__ yio, float* __restrict__ bwo) {
  __shared__ float dwl[16 * 128];
  __shared__ float owl[128];
  for (int i = threadIdx.x; i < 2048; i += 256) dwl[i] = dw[i];
  if (threadIdx.x < 128) owl[threadIdx.x] = oww[threadIdx.x];
  __syncthreads();
  int p = blockIdx.x * 256 + threadIdx.x;
  int b = p / 6144;
  int rem = p % 6144;
  int y = rem / 96;
  int x = rem % 96;

  float lg[16];
#pragma unroll
  for (int j = 0; j < 16; ++j) lg[j] = dbias[j];
  float oa = obias[0];
  const float* fp = x4 + (b * 128) * 6144 + rem;
  for (int ic = 0; ic < 128; ++ic) {
    float f = fp[ic * 6144];
#pragma unroll
    for (int j = 0; j < 16; ++j) lg[j] += f * dwl[j * 128 + ic];
    oa += f * owl[ic];
  }
  float m = lg[0];
#pragma unroll
  for (int j = 1; j < 16; ++j) m = fmaxf(m, lg[j]);
  float se = 0.f, sz = 0.f;
#pragma unroll
  for (int j = 0; j < 16; ++j) {
    float e = expf(lg[j] - m);
    se += e;
    sz += e * (1.0f + (float)j * (59.0f / 15.0f));
  }
  float z = sz / se;
  float op = 1.f / (1.f + expf(-oa));

  const float* K = camK + b * 9;
  float fx = fmaxf(K[0], 1e-6f), fy = fmaxf(K[4], 1e-6f);
  float cx = K[2], cy = K[5];
  float xs = ((float)x + 0.5f) * 16.0f;
  float ys = ((float)y + 0.5f) * 16.0f;
  float xc = (xs - cx) * z / fx;
  float yc = (ys - cy) * z / fy;
  const float* T = Tlc + b * 16;
  float xw = T[0] * xc + T[1] * yc + T[2] * z + T[3];
  float yw = T[4] * xc + T[5] * yc + T[6] * z + T[7];
  float zw = T[8] * xc + T[9] * yc + T[10] * z + T[11];
  float xif = floorf((xw - (-51.2f)) / 0.4f);
  float yif = floorf((yw - (-51.2f)) / 0.4f);
  int xi = (int)xif, yi = (int)yif;
  bool inb = xi >= 0 && xi < 256 && yi >= 0 && yi < 256 && zw >= -5.0f && zw < 3.0f;
  float bw = (op >= 0.05f && inb) ? op : 0.f;
  xio[p] = xi;
  yio[p] = yi;
  bwo[p] = bw;
}

__global__ __launch_bounds__(256) void zerof4(float4* __restrict__ p) {
  int i = blockIdx.x * 256 + threadIdx.x;
  p[i] = make_float4(0.f, 0.f, 0.f, 0.f);
}

// 9-tap Gaussian scatter. (R1-verbatim)
__global__ __launch_bounds__(256) void splat(
    const float* __restrict__ feats, const int* __restrict__ xi,
    const int* __restrict__ yi, const float* __restrict__ bw,
    float* __restrict__ canvas, float* __restrict__ wacc) {
  int t = blockIdx.x * 256 + threadIdx.x;
  int c = t & 63;
  int p = t >> 6;
  float w0 = bw[p];
  if (w0 == 0.f) return;
  int X = xi[p], Y = yi[p];
  int b = p / 6144;
  float fv = feats[t];
  float* cb = canvas + ((size_t)b << 22);
  float* wb = wacc + (b << 16);
  const float kwt[3] = {1.0f, 0.45783335f, 0.20961137f};
#pragma unroll
  for (int dy = -1; dy <= 1; ++dy) {
    int ty = Y + dy;
    if (ty < 0 || ty > 255) continue;
#pragma unroll
    for (int dx = -1; dx <= 1; ++dx) {
      int tx = X + dx;
      if (tx < 0 || tx > 255) continue;
      float kw = kwt[dx * dx + dy * dy];
      atomicAdd(&cb[(((ty << 8) + tx) << 6) + c], fv * w0 * kw);
      if (c == 0) atomicAdd(&wb[(ty << 8) + tx], w0 * kw);
    }
  }
}

// normalize + NHWC->NCHW transpose. (R1-verbatim)
__global__ __launch_bounds__(256) void normalize_out(
    const float* __restrict__ canvas, const float* __restrict__ wacc,
    float* __restrict__ out) {
  __shared__ float tile[64][65];
  int blk = blockIdx.x;
  int b = blk >> 10;
  int s0 = (blk & 1023) << 6;
  int tid = threadIdx.x;
  const float* cb = canvas + ((size_t)b << 22);
  const float* wb = wacc + (b << 16);
#pragma unroll
  for (int it = 0; it < 16; ++it) {
    int l = it * 256 + tid;
    int pix = l >> 6, ch = l & 63;
    float w = wb[s0 + pix];
    float n = w > 0.f ? 1.f / fmaxf(w, 1e-6f) : 0.f;
    tile[pix][ch] = cb[(size_t)(s0 + pix) * 64 + ch] * n;
  }
  __syncthreads();
  float* ob = out + ((size_t)b << 22);
#pragma unroll
  for (int it = 0; it < 16; ++it) {
    int l = it * 256 + tid;
    int ch = l >> 6, pix = l & 63;
    ob[(size_t)ch * 65536 + s0 + pix] = tile[pix][ch];
  }
}

extern "C" void kernel_launch(void* const* d_in, const int* in_sizes, int n_in,
                              void* d_out, int out_size, void* d_ws, size_t ws_size,
                              hipStream_t stream) {
  const float* images = (const float*)d_in[0];
  const float* camK   = (const float*)d_in[1];
  const float* Tlc    = (const float*)d_in[2];
  const float* w1 = (const float*)d_in[3];
  const float* s1 = (const float*)d_in[4];
  const float* b1 = (const float*)d_in[5];
  const float* w2 = (const float*)d_in[6];
  const float* s2 = (const float*)d_in[7];
  const float* b2 = (const float*)d_in[8];
  const float* w3 = (const float*)d_in[9];
  const float* s3 = (const float*)d_in[10];
  const float* b3 = (const float*)d_in[11];
  const float* w4 = (const float*)d_in[12];
  const float* s4 = (const float*)d_in[13];
  const float* b4 = (const float*)d_in[14];
  const float* fw1 = (const float*)d_in[15];
  const float* fs1 = (const float*)d_in[16];
  const float* fb1 = (const float*)d_in[17];
  const float* fw2 = (const float*)d_in[18];
  const float* fbias2 = (const float*)d_in[19];
  const float* dw = (const float*)d_in[20];
  const float* dbias = (const float*)d_in[21];
  const float* ow = (const float*)d_in[22];
  const float* obias = (const float*)d_in[23];
  float* out = (float*)d_out;

  // workspace layout (floats), aliased (same as R1/R5/R6):
  //   A [50,331,648]: conv1 out -> conv3 out (12.58M) -> canvas(16.78M)+wacc(0.26M)
  //   B [25,165,824]: conv2 out -> c4(3.15M) | fh(3.15M) | feats(1.57M) | xi/yi/bw
  float* ws = (float*)d_ws;
  float* A = ws;
  float* Bb = ws + 50331648;
  float* c4   = Bb;
  float* fhb  = Bb + 3145728;
  float* ftb  = Bb + 6291456;
  int*   xib  = (int*)(Bb + 7864320);
  int*   yib  = xib + 24576;
  float* bwb  = (float*)(yib + 24576);
  float* canvas = A;
  float* waccb  = A + 16777216;

  // Temporal chunk interleave (4 pairs — R3 best): conv1 rows [128k,128k+128)
  // then conv2 rows [64k,64k+64) (reads conv1 rows [128k-1,128k+127] ->
  // chunks <=k only; stream order satisfies the dependency).
  for (int k = 0; k < 4; ++k) {
    conv3x3_chunk<2, 5, 192><<<49152, 256, 0, stream>>>(
        images, w1, s1, b1, A, 3, 1024, 1536, 32, 512, 768, k);
    conv3x3_chunk<2, 6, 48><<<24576, 256, 0, stream>>>(
        A, w2, s2, b2, Bb, 32, 512, 768, 64, 256, 384, k);
  }
  // conv3, conv4, fw1: R3 grid shapes (768 blocks — measured best).
  conv3x3_t<2, 64, 64, 128, 8, 8, 32><<<768, 256, 0, stream>>>(
      Bb, w3, s3, b3, A, 256, 384, 128, 192);
  conv3x3_t<2, 128, 32, 128, 4, 8, 16><<<768, 256, 0, stream>>>(
      A, w4, s4, b4, c4, 128, 192, 64, 96);
  conv3x3_t<1, 128, 32, 128, 4, 8, 16><<<768, 256, 0, stream>>>(
      c4, fw1, fs1, fb1, fhb, 64, 96, 64, 96);
  feat_head<<<6144, 256, 0, stream>>>(fhb, fw2, fbias2, ftb);
  depth_head<<<96, 256, 0, stream>>>(c4, dw, dbias, ow, obias, camK, Tlc, xib, yib, bwb);
  zerof4<<<16640, 256, 0, stream>>>((float4*)canvas);
  splat<<<6144, 256, 0, stream>>>(ftb, xib, yib, bwb, canvas, waccb);
  normalize_out<<<4096, 256, 0, stream>>>(canvas, waccb, out);
}

// Round 8
// 2806.734 us; speedup vs baseline: 1.0835x; 1.0079x over previous
//
#include <hip/hip_runtime.h>
#include <math.h>

// ---------------- problem constants ----------------
// B=4, H=1024, W=1536; Hf=64, Wf=96; C=64; grid 256x256; D=16 depth bins.
// conv chain: (3,1024,1536)->(32,512,768)->(64,256,384)->(128,128,192)->(128,64,96)
//
// NUMERICS LEDGER:
//  R1 naive conv1/conv2: PASS 0.015625. Every restructured conv1/conv2 BODY
//  fails at exactly 0.203125 (knife-edge p* flips between fast-math
//  realizations). conv3/4/fw1 tiled (__builtin_fmaf) PASS; R5 changed
//  TY/TX/NOC4 blocking and absmax was unmoved -> thread-ownership remaps
//  (per-output ic->ky->kx fmaf chain preserved) are BIT-IDENTICAL-safe.
//  => conv1/conv2 BODIES LOCKED (R1 source); launch-order permutations ok.
//
//  SCHEDULE LEDGER (R3/R7 = verified best, 2829us):
//   R0 no interleave: conv2 1690us (L3 overflow -> HBM misses).
//   R3 4-chunk interleave: conv2 4x364us (request-rate floor: stride-2
//      lanes -> 8 lines/wave-load, body locked). BEST 2829us.
//   R4 8-chunk: REGRESSED (cross-dispatch L2 reuse impossible: kernel-
//      boundary release/acquire invalidates per-XCD L2).
//   R5 tile split (more blocks): REGRESSED (staging overhead > occ gain).
//   R6 4-ic staging: REGRESSED (LDS 7->27KB, occ 32->18%).
//   R7 wl row pad (bank-conflict fix): neutral total; kept (harmless).
//   THIS ROUND: conv3/4/fw1 are LDS-READ-bound, not occupancy-bound:
//      conv3 issued 72 ds_read_b128 (weights, single-use) per thread-ic vs
//      576 fmas -> ~864cy LDS vs 576cy VALU (VALUBusy 49%). Reblock
//      NOC4/2, PIX*2: weight reads halve (72->36, 36->18), fma count /
//      LDS / grid unchanged. Outputs bit-identical.

// ---------- R1-verbatim naive conv body; chunked launch permutation ----------
// conv1: SPG=192, grid/chunk = 8*192*32 = 49152 (chunk k = rows [128k,128k+128))
// conv2: SPG=48,  grid/chunk = 8*48*64  = 24576 (chunk k = rows [64k,64k+64))
// x = blk&7 -> XCD (round-robin): b = x>>1, g = x&1 (row-half within chunk).
template<int STRIDE, int OCL2, int SPG>
__global__ __launch_bounds__(256) void conv3x3_chunk(
    const float* __restrict__ in, const float* __restrict__ wgt,
    const float* __restrict__ scl, const float* __restrict__ sft,
    float* __restrict__ out,
    int IC, int IH, int IW, int OC, int OH, int OW, int k) {
  __shared__ float wl[1152];  // up to IC=128 * 9
  // --- launch-order permutation (bijection on 256-output chunks) ---
  int chw = (OH * OW) >> 8;            // slabs per (b,oc) plane
  int x = blockIdx.x & 7;              // -> XCD (round-robin dispatch heuristic)
  int y = blockIdx.x >> 3;
  int b_sel = x >> 1;                  // batch pinned to XCD pair
  int g = x & 1;                       // row-half group within chunk
  int oc_r = y & ((1 << OCL2) - 1);    // oc fastest: same-slab blocks adjacent in time
  int s_loc = y >> OCL2;               // [0, SPG)
  int s = k * (2 * SPG) + g * SPG + s_loc;   // global slab within (b,oc) plane
  int chunk = (b_sel * OC + oc_r) * chw + s;
  int idx = chunk * 256 + threadIdx.x;
  // --- body identical to R1 naive kernel from here on ---
  int ox = idx % OW;
  int tmp = idx / OW;
  int oy = tmp % OH;
  tmp /= OH;
  int oc = tmp % OC;
  int b = tmp / OC;
  int wn = IC * 9;
  for (int i = threadIdx.x; i < wn; i += 256) wl[i] = wgt[oc * wn + i];
  __syncthreads();

  const float* ip0 = in + (b * IC) * IH * IW;
  int iy0 = oy * STRIDE - 1;
  int ix0 = ox * STRIDE - 1;
  int plane = IH * IW;
  float acc = 0.f;
  if (iy0 >= 0 && iy0 + 2 < IH && ix0 >= 0 && ix0 + 2 < IW) {
    const float* ip = ip0 + iy0 * IW + ix0;
    const float* wp = wl;
    for (int ic = 0; ic < IC; ++ic) {
#pragma unroll
      for (int ky = 0; ky < 3; ++ky) {
        const float* r = ip + ky * IW;
        acc += r[0] * wp[ky * 3 + 0];
        acc += r[1] * wp[ky * 3 + 1];
        acc += r[2] * wp[ky * 3 + 2];
      }
      ip += plane;
      wp += 9;
    }
  } else {
    for (int ic = 0; ic < IC; ++ic) {
      const float* ip = ip0 + ic * plane;
      const float* wp = wl + ic * 9;
#pragma unroll
      for (int ky = 0; ky < 3; ++ky) {
        int iy = iy0 + ky;
        if (iy < 0 || iy >= IH) continue;
#pragma unroll
        for (int kx = 0; kx < 3; ++kx) {
          int ix = ix0 + kx;
          if (ix < 0 || ix >= IW) continue;
          acc += ip[iy * IW + ix] * wp[ky * 3 + kx];
        }
      }
    }
  }
  float r = acc * scl[oc] + sft[oc];
  out[idx] = r > 0.f ? r : 0.f;
}

// ---------- tiled conv (conv3, conv4, fw1) — padded wl + PIX-heavy blocking ----------
// Per-output fmaf chain ic->ky->kx unchanged (bit-identical). OCP = OCB+4
// pads each kk-row of wl (bank-conflict-free staging writes).
template<int STRIDE, int IC, int OCB, int OCT, int NOC4, int TY, int TX>
__global__ __launch_bounds__(256) void conv3x3_t(
    const float* __restrict__ in, const float* __restrict__ wgt,
    const float* __restrict__ scl, const float* __restrict__ sft,
    float* __restrict__ out, int IH, int IW, int OH, int OW) {
  constexpr int OCG = NOC4 * 4;
  constexpr int NOCG = OCB / OCG;
  constexpr int NPIX_T = 256 / NOCG;
  constexpr int PIX = (TY * TX) / NPIX_T;
  constexpr int PH = (TY - 1) * STRIDE + 3;
  constexpr int PW = (TX - 1) * STRIDE + 3;
  constexpr int OCP = OCB + 4;         // padded row: stride 68/36 floats
  __shared__ float patch[PH * PW];
  __shared__ float wl[9 * OCP];

  int NTY = OH / TY, NTX = OW / TX;
  int ntiles = 4 * NTY * NTX;
  int ocs = blockIdx.x / ntiles;
  int r = blockIdx.x % ntiles;
  int b = r / (NTY * NTX);
  int t = r % (NTY * NTX);
  int tyi = t / NTX, txi = t % NTX;
  int oc_base = ocs * OCB;

  int tid = threadIdx.x;
  int pid = tid % NPIX_T;
  int ocg = tid / NPIX_T;

  int off[PIX], pyv[PIX], pxv[PIX];
#pragma unroll
  for (int i = 0; i < PIX; ++i) {
    int p = i * NPIX_T + pid;
    pyv[i] = p / TX;
    pxv[i] = p % TX;
    off[i] = (pyv[i] * STRIDE) * PW + pxv[i] * STRIDE;
  }

  float4 acc[PIX][NOC4];
#pragma unroll
  for (int i = 0; i < PIX; ++i)
#pragma unroll
    for (int j = 0; j < NOC4; ++j) acc[i][j] = make_float4(0.f, 0.f, 0.f, 0.f);

  const size_t plane_in = (size_t)IH * IW;
  const float* ibase = in + (size_t)b * IC * plane_in;
  int iy0 = tyi * TY * STRIDE - 1;
  int ix0 = txi * TX * STRIDE - 1;

#pragma unroll 1
  for (int ic = 0; ic < IC; ++ic) {
    const float* ip = ibase + (size_t)ic * plane_in;
    for (int i = tid; i < PH * PW; i += 256) {
      int py = i / PW, px = i % PW;
      int iy = iy0 + py, ix = ix0 + px;
      float v = 0.f;
      if (iy >= 0 && iy < IH && ix >= 0 && ix < IW) v = ip[(size_t)iy * IW + ix];
      patch[i] = v;
    }
    for (int i = tid; i < 9 * OCB; i += 256) {
      int oc = i / 9, kk = i % 9;
      wl[kk * OCP + oc] = wgt[((size_t)(oc_base + oc) * IC + ic) * 9 + kk];
    }
    __syncthreads();

    const float4* wl4 = (const float4*)wl;
#pragma unroll
    for (int ky = 0; ky < 3; ++ky) {
#pragma unroll
      for (int kx = 0; kx < 3; ++kx) {
        float pv[PIX];
#pragma unroll
        for (int i = 0; i < PIX; ++i) pv[i] = patch[off[i] + ky * PW + kx];
        const float4* wr = wl4 + (ky * 3 + kx) * (OCP / 4) + ocg * NOC4;
#pragma unroll
        for (int j = 0; j < NOC4; ++j) {
          float4 w = wr[j];
#pragma unroll
          for (int i = 0; i < PIX; ++i) {
            acc[i][j].x = __builtin_fmaf(pv[i], w.x, acc[i][j].x);
            acc[i][j].y = __builtin_fmaf(pv[i], w.y, acc[i][j].y);
            acc[i][j].z = __builtin_fmaf(pv[i], w.z, acc[i][j].z);
            acc[i][j].w = __builtin_fmaf(pv[i], w.w, acc[i][j].w);
          }
        }
      }
    }
    __syncthreads();
  }

  int plane = OH * OW;
#pragma unroll
  for (int i = 0; i < PIX; ++i) {
    int oy = tyi * TY + pyv[i];
    int ox = txi * TX + pxv[i];
#pragma unroll
    for (int j = 0; j < NOC4; ++j) {
      int oc0 = oc_base + ocg * OCG + j * 4;
      float4 v = acc[i][j];
      float4 sc = ((const float4*)scl)[oc0 >> 2];
      float4 sh = ((const float4*)sft)[oc0 >> 2];
      float rx = __builtin_fmaf(v.x, sc.x, sh.x);
      float ry = __builtin_fmaf(v.y, sc.y, sh.y);
      float rz = __builtin_fmaf(v.z, sc.z, sh.z);
      float rw = __builtin_fmaf(v.w, sc.w, sh.w);
      rx = rx > 0.f ? rx : 0.f;
      ry = ry > 0.f ? ry : 0.f;
      rz = rz > 0.f ? rz : 0.f;
      rw = rw > 0.f ? rw : 0.f;
      size_t base = ((size_t)b * OCT + oc0) * plane + oy * OW + ox;
      out[base] = rx;
      out[base + plane] = ry;
      out[base + 2 * (size_t)plane] = rz;
      out[base + 3 * (size_t)plane] = rw;
    }
  }
}

// 1x1 conv 128->64 + bias, output (B, Hf, Wf, C). (R1-verbatim)
__global__ __launch_bounds__(256) void feat_head(
    const float* __restrict__ fh, const float* __restrict__ fw2,
    const float* __restrict__ fb, float* __restrict__ feats) {
  __shared__ float wl[128 * 64];
  for (int i = threadIdx.x; i < 8192; i += 256) {
    int c = i & 63, ic = i >> 6;
    wl[i] = fw2[c * 128 + ic];
  }
  __syncthreads();
  int t = blockIdx.x * 256 + threadIdx.x;
  int c = t & 63;
  int p = t >> 6;
  int b = p / 6144;
  int rem = p % 6144;
  const float* fp = fh + (b * 128) * 6144 + rem;
  float acc = fb[c];
#pragma unroll 4
  for (int ic = 0; ic < 128; ++ic) acc += fp[ic * 6144] * wl[(ic << 6) + c];
  feats[t] = acc;
}

// depth/opacity heads + backprojection + voxelization. (R1-verbatim)
__global__ __launch_bounds__(256) void depth_head(
    const float* __restrict__ x4, const float* __restrict__ dw,
    const float* __restrict__ dbias, const float* __restrict__ oww,
    const float* __restrict__ obias, const float* __restrict__ camK,
    const float* __restrict__ Tlc,
    int* __restrict__ xio, int* __restrict__ yio, float* __restrict__ bwo) {
  __shared__ float dwl[16 * 128];
  __shared__ float owl[128];
  for (int i = threadIdx.x; i < 2048; i += 256) dwl[i] = dw[i];
  if (threadIdx.x < 128) owl[threadIdx.x] = oww[threadIdx.x];
  __syncthreads();
  int p = blockIdx.x * 256 + threadIdx.x;
  int b = p / 6144;
  int rem = p % 6144;
  int y = rem / 96;
  int x = rem % 96;

  float lg[16];
#pragma unroll
  for (int j = 0; j < 16; ++j) lg[j] = dbias[j];
  float oa = obias[0];
  const float* fp = x4 + (b * 128) * 6144 + rem;
  for (int ic = 0; ic < 128; ++ic) {
    float f = fp[ic * 6144];
#pragma unroll
    for (int j = 0; j < 16; ++j) lg[j] += f * dwl[j * 128 + ic];
    oa += f * owl[ic];
  }
  float m = lg[0];
#pragma unroll
  for (int j = 1; j < 16; ++j) m = fmaxf(m, lg[j]);
  float se = 0.f, sz = 0.f;
#pragma unroll
  for (int j = 0; j < 16; ++j) {
    float e = expf(lg[j] - m);
    se += e;
    sz += e * (1.0f + (float)j * (59.0f / 15.0f));
  }
  float z = sz / se;
  float op = 1.f / (1.f + expf(-oa));

  const float* K = camK + b * 9;
  float fx = fmaxf(K[0], 1e-6f), fy = fmaxf(K[4], 1e-6f);
  float cx = K[2], cy = K[5];
  float xs = ((float)x + 0.5f) * 16.0f;
  float ys = ((float)y + 0.5f) * 16.0f;
  float xc = (xs - cx) * z / fx;
  float yc = (ys - cy) * z / fy;
  const float* T = Tlc + b * 16;
  float xw = T[0] * xc + T[1] * yc + T[2] * z + T[3];
  float yw = T[4] * xc + T[5] * yc + T[6] * z + T[7];
  float zw = T[8] * xc + T[9] * yc + T[10] * z + T[11];
  float xif = floorf((xw - (-51.2f)) / 0.4f);
  float yif = floorf((yw - (-51.2f)) / 0.4f);
  int xi = (int)xif, yi = (int)yif;
  bool inb = xi >= 0 && xi < 256 && yi >= 0 && yi < 256 && zw >= -5.0f && zw < 3.0f;
  float bw = (op >= 0.05f && inb) ? op : 0.f;
  xio[p] = xi;
  yio[p] = yi;
  bwo[p] = bw;
}

__global__ __launch_bounds__(256) void zerof4(float4* __restrict__ p) {
  int i = blockIdx.x * 256 + threadIdx.x;
  p[i] = make_float4(0.f, 0.f, 0.f, 0.f);
}

// 9-tap Gaussian scatter. (R1-verbatim)
__global__ __launch_bounds__(256) void splat(
    const float* __restrict__ feats, const int* __restrict__ xi,
    const int* __restrict__ yi, const float* __restrict__ bw,
    float* __restrict__ canvas, float* __restrict__ wacc) {
  int t = blockIdx.x * 256 + threadIdx.x;
  int c = t & 63;
  int p = t >> 6;
  float w0 = bw[p];
  if (w0 == 0.f) return;
  int X = xi[p], Y = yi[p];
  int b = p / 6144;
  float fv = feats[t];
  float* cb = canvas + ((size_t)b << 22);
  float* wb = wacc + (b << 16);
  const float kwt[3] = {1.0f, 0.45783335f, 0.20961137f};
#pragma unroll
  for (int dy = -1; dy <= 1; ++dy) {
    int ty = Y + dy;
    if (ty < 0 || ty > 255) continue;
#pragma unroll
    for (int dx = -1; dx <= 1; ++dx) {
      int tx = X + dx;
      if (tx < 0 || tx > 255) continue;
      float kw = kwt[dx * dx + dy * dy];
      atomicAdd(&cb[(((ty << 8) + tx) << 6) + c], fv * w0 * kw);
      if (c == 0) atomicAdd(&wb[(ty << 8) + tx], w0 * kw);
    }
  }
}

// normalize + NHWC->NCHW transpose. (R1-verbatim)
__global__ __launch_bounds__(256) void normalize_out(
    const float* __restrict__ canvas, const float* __restrict__ wacc,
    float* __restrict__ out) {
  __shared__ float tile[64][65];
  int blk = blockIdx.x;
  int b = blk >> 10;
  int s0 = (blk & 1023) << 6;
  int tid = threadIdx.x;
  const float* cb = canvas + ((size_t)b << 22);
  const float* wb = wacc + (b << 16);
#pragma unroll
  for (int it = 0; it < 16; ++it) {
    int l = it * 256 + tid;
    int pix = l >> 6, ch = l & 63;
    float w = wb[s0 + pix];
    float n = w > 0.f ? 1.f / fmaxf(w, 1e-6f) : 0.f;
    tile[pix][ch] = cb[(size_t)(s0 + pix) * 64 + ch] * n;
  }
  __syncthreads();
  float* ob = out + ((size_t)b << 22);
#pragma unroll
  for (int it = 0; it < 16; ++it) {
    int l = it * 256 + tid;
    int ch = l >> 6, pix = l & 63;
    ob[(size_t)ch * 65536 + s0 + pix] = tile[pix][ch];
  }
}

extern "C" void kernel_launch(void* const* d_in, const int* in_sizes, int n_in,
                              void* d_out, int out_size, void* d_ws, size_t ws_size,
                              hipStream_t stream) {
  const float* images = (const float*)d_in[0];
  const float* camK   = (const float*)d_in[1];
  const float* Tlc    = (const float*)d_in[2];
  const float* w1 = (const float*)d_in[3];
  const float* s1 = (const float*)d_in[4];
  const float* b1 = (const float*)d_in[5];
  const float* w2 = (const float*)d_in[6];
  const float* s2 = (const float*)d_in[7];
  const float* b2 = (const float*)d_in[8];
  const float* w3 = (const float*)d_in[9];
  const float* s3 = (const float*)d_in[10];
  const float* b3 = (const float*)d_in[11];
  const float* w4 = (const float*)d_in[12];
  const float* s4 = (const float*)d_in[13];
  const float* b4 = (const float*)d_in[14];
  const float* fw1 = (const float*)d_in[15];
  const float* fs1 = (const float*)d_in[16];
  const float* fb1 = (const float*)d_in[17];
  const float* fw2 = (const float*)d_in[18];
  const float* fbias2 = (const float*)d_in[19];
  const float* dw = (const float*)d_in[20];
  const float* dbias = (const float*)d_in[21];
  const float* ow = (const float*)d_in[22];
  const float* obias = (const float*)d_in[23];
  float* out = (float*)d_out;

  // workspace layout (floats), aliased (same as R1/R5/R6):
  //   A [50,331,648]: conv1 out -> conv3 out (12.58M) -> canvas(16.78M)+wacc(0.26M)
  //   B [25,165,824]: conv2 out -> c4(3.15M) | fh(3.15M) | feats(1.57M) | xi/yi/bw
  float* ws = (float*)d_ws;
  float* A = ws;
  float* Bb = ws + 50331648;
  float* c4   = Bb;
  float* fhb  = Bb + 3145728;
  float* ftb  = Bb + 6291456;
  int*   xib  = (int*)(Bb + 7864320);
  int*   yib  = xib + 24576;
  float* bwb  = (float*)(yib + 24576);
  float* canvas = A;
  float* waccb  = A + 16777216;

  // Temporal chunk interleave (4 pairs — R3 best): conv1 rows [128k,128k+128)
  // then conv2 rows [64k,64k+64) (reads conv1 rows [128k-1,128k+127] ->
  // chunks <=k only; stream order satisfies the dependency).
  for (int k = 0; k < 4; ++k) {
    conv3x3_chunk<2, 5, 192><<<49152, 256, 0, stream>>>(
        images, w1, s1, b1, A, 3, 1024, 1536, 32, 512, 768, k);
    conv3x3_chunk<2, 6, 48><<<24576, 256, 0, stream>>>(
        A, w2, s2, b2, Bb, 32, 512, 768, 64, 256, 384, k);
  }
  // conv3: NOC4 8->4 (PIX 2->4): weight ds_read_b128 per thread-ic 72->36.
  conv3x3_t<2, 64, 64, 128, 4, 8, 32><<<768, 256, 0, stream>>>(
      Bb, w3, s3, b3, A, 256, 384, 128, 192);
  // conv4/fw1: NOC4 4->2 (PIX 1->2): weight reads 36->18.
  conv3x3_t<2, 128, 32, 128, 2, 8, 16><<<768, 256, 0, stream>>>(
      A, w4, s4, b4, c4, 128, 192, 64, 96);
  conv3x3_t<1, 128, 32, 128, 2, 8, 16><<<768, 256, 0, stream>>>(
      c4, fw1, fs1, fb1, fhb, 64, 96, 64, 96);
  feat_head<<<6144, 256, 0, stream>>>(fhb, fw2, fbias2, ftb);
  depth_head<<<96, 256, 0, stream>>>(c4, dw, dbias, ow, obias, camK, Tlc, xib, yib, bwb);
  zerof4<<<16640, 256, 0, stream>>>((float4*)canvas);
  splat<<<6144, 256, 0, stream>>>(ftb, xib, yib, bwb, canvas, waccb);
  normalize_out<<<4096, 256, 0, stream>>>(canvas, waccb, out);
}